// Round 1
// baseline (1361.517 us; speedup 1.0000x reference)
//
#include <hip/hip_runtime.h>

typedef float f4 __attribute__((ext_vector_type(4)));

#define BATCH 8
#define CH 128
#define NPIX 4096

// ---------------- weight transpose: wt[m][c][o] = W_m[o][c] ----------------
__global__ __launch_bounds__(256) void wtrans_kernel(const float* __restrict__ Wq,
                                                     const float* __restrict__ Wk,
                                                     const float* __restrict__ Wv,
                                                     float* __restrict__ wt) {
    int m = blockIdx.x;
    const float* W = (m == 0) ? Wq : (m == 1) ? Wk : Wv;
    float* o = wt + m * CH * CH;
    for (int idx = threadIdx.x; idx < CH * CH; idx += 256) {
        int r = idx >> 7;
        int c = idx & (CH - 1);
        o[c * CH + r] = W[idx];
    }
}

// ---------------- QKV projection: Y[b][o][n] = sum_c W[o][c] X[b][c][n] + bias[o] ----------------
// grid: 3 * 8 * 64 blocks (matrix, batch, 64-pixel chunk), 256 threads
__global__ __launch_bounds__(256) void qkv_kernel(const float* __restrict__ x1,
                                                  const float* __restrict__ x2,
                                                  const float* __restrict__ wt,
                                                  const float* __restrict__ bq,
                                                  const float* __restrict__ bk,
                                                  const float* __restrict__ bv,
                                                  float* __restrict__ qws,
                                                  float* __restrict__ kws,
                                                  float* __restrict__ vws) {
    __shared__ __align__(16) float WTs[CH * CH];  // WT[c][o], 64 KB
    __shared__ __align__(16) float Xs[CH * 64];   // X[c][nn], 32 KB

    int bid = blockIdx.x;
    int m = bid >> 9;          // 0..2
    int rem = bid & 511;
    int b = rem & 7;
    int n0 = (rem >> 3) << 6;  // pixel chunk base

    const float* X = ((m == 0) ? x1 : x2) + (size_t)b * CH * NPIX;
    const float* WTm = wt + m * CH * CH;
    const float* bias = (m == 0) ? bq : (m == 1) ? bk : bv;
    float* Y = ((m == 0) ? qws : (m == 1) ? kws : vws) + (size_t)b * CH * NPIX;

    int tid = threadIdx.x;

    // stage WT (contiguous) and X chunk (row-contiguous, coalesced)
#pragma unroll
    for (int r = 0; r < 16; ++r) {
        int fi = r * 1024 + tid * 4;
        *(f4*)&WTs[fi] = *(const f4*)&WTm[fi];
    }
#pragma unroll
    for (int r = 0; r < 8; ++r) {
        int q4 = r * 256 + tid;
        int c = q4 >> 4;
        int nn = (q4 & 15) << 2;
        *(f4*)&Xs[c * 64 + nn] = *(const f4*)&X[c * NPIX + n0 + nn];
    }
    __syncthreads();

    int to = (tid & 15) << 2;  // output-channel quad base (16 quads cover o=0..63; +64 for hi)
    int tn = (tid >> 4) << 2;  // pixel quad base (16 quads cover nn=0..63)

    float a0[4][4] = {{0.f}}, a1[4][4] = {{0.f}};
#pragma unroll 4
    for (int c = 0; c < CH; ++c) {
        f4 xv = *(const f4*)&Xs[c * 64 + tn];
        f4 w0 = *(const f4*)&WTs[c * CH + to];
        f4 w1 = *(const f4*)&WTs[c * CH + 64 + to];
#pragma unroll
        for (int u = 0; u < 4; ++u) {
#pragma unroll
            for (int w = 0; w < 4; ++w) {
                a0[u][w] += w0[u] * xv[w];
                a1[u][w] += w1[u] * xv[w];
            }
        }
    }

#pragma unroll
    for (int u = 0; u < 4; ++u) {
        int o0 = to + u;
        int o1 = 64 + to + u;
        float bb0 = bias[o0];
        float bb1 = bias[o1];
        f4 r0, r1;
#pragma unroll
        for (int w = 0; w < 4; ++w) {
            r0[w] = a0[u][w] + bb0;
            r1[w] = a1[u][w] + bb1;
        }
        *(f4*)&Y[o0 * NPIX + n0 + tn] = r0;
        *(f4*)&Y[o1 * NPIX + n0 + tn] = r1;
    }
}

// ---------------- flash attention ----------------
// grid: 8 * 64 blocks (batch = blockIdx&7 for XCD/L2 locality, 64-query tile), 256 threads
__global__ __launch_bounds__(256) void attn_kernel(const float* __restrict__ qws,
                                                   const float* __restrict__ kws,
                                                   const float* __restrict__ vws,
                                                   float* __restrict__ out) {
    __shared__ __align__(16) float QsT[CH * 64];   // Q^T[c][i]  32 KB
    __shared__ __align__(16) float KsT[CH * 64];   // K^T[c][j]  32 KB
    __shared__ __align__(16) float VsT[CH * 68];   // V^T[c][j] (pad 68) 34 KB
    __shared__ __align__(16) float PT[64 * 68];    // P^T[j][i] (pad 68) 17 KB
    __shared__ float red[64 * 17];                 // per-row partials
    __shared__ float mprev[64];
    __shared__ float lsum[64];
    __shared__ float alpha_s[64];

    int tid = threadIdx.x;
    int b = blockIdx.x & 7;
    int i0g = (blockIdx.x >> 3) << 6;

    const float* Q = qws + (size_t)b * CH * NPIX;
    const float* K = kws + (size_t)b * CH * NPIX;
    const float* V = vws + (size_t)b * CH * NPIX;

    if (tid < 64) {
        mprev[tid] = -1e30f;
        lsum[tid] = 0.0f;
    }

    // stage Q tile once: QsT[c][i] = Q[c][i0g+i]
#pragma unroll
    for (int r = 0; r < 8; ++r) {
        int q4 = r * 256 + tid;
        int c = q4 >> 4;
        int nn = (q4 & 15) << 2;
        *(f4*)&QsT[c * 64 + nn] = *(const f4*)&Q[c * NPIX + i0g + nn];
    }

    int ti = (tid & 15) << 2;  // i-quad base (S rows / PV rows / output rows)
    int tj = tid >> 4;         // S: j-quad index 0..15 ; PV: channel base 0..15

    float oacc[8][4] = {{0.f}};  // [w -> channel tj+16w][u -> i ti+u]
    __syncthreads();

    for (int jt = 0; jt < 64; ++jt) {
        int j0g = jt << 6;
        // stage K,V tiles
#pragma unroll
        for (int r = 0; r < 8; ++r) {
            int q4 = r * 256 + tid;
            int c = q4 >> 4;
            int nn = (q4 & 15) << 2;
            *(f4*)&KsT[c * 64 + nn] = *(const f4*)&K[c * NPIX + j0g + nn];
            *(f4*)&VsT[c * 68 + nn] = *(const f4*)&V[c * NPIX + j0g + nn];
        }
        __syncthreads();  // (1)

        // S[i][j] = sum_c Q^T[c][i] * K^T[c][j]
        float s[4][4] = {{0.f}};
#pragma unroll 4
        for (int c = 0; c < CH; ++c) {
            f4 qv = *(const f4*)&QsT[c * 64 + ti];
            f4 kv = *(const f4*)&KsT[c * 64 + (tj << 2)];
#pragma unroll
            for (int u = 0; u < 4; ++u)
#pragma unroll
                for (int v = 0; v < 4; ++v) s[u][v] += qv[u] * kv[v];
        }

        // partial row max
#pragma unroll
        for (int u = 0; u < 4; ++u) {
            float pm = fmaxf(fmaxf(s[u][0], s[u][1]), fmaxf(s[u][2], s[u][3]));
            red[(ti + u) * 17 + tj] = pm;
        }
        __syncthreads();  // (2)

        if (tid < 64) {
            float mt = red[tid * 17];
#pragma unroll
            for (int t = 1; t < 16; ++t) mt = fmaxf(mt, red[tid * 17 + t]);
            float mo = mprev[tid];
            float mn = fmaxf(mo, mt);
            alpha_s[tid] = __expf(mo - mn);
            mprev[tid] = mn;
        }
        __syncthreads();  // (3)

        // P = exp(S - m_new), write P^T[j][i], accumulate partial row sums
        float mrow[4];
#pragma unroll
        for (int u = 0; u < 4; ++u) mrow[u] = mprev[ti + u];
        float rs[4] = {0.f, 0.f, 0.f, 0.f};
#pragma unroll
        for (int v = 0; v < 4; ++v) {
            f4 pw;
#pragma unroll
            for (int u = 0; u < 4; ++u) {
                float p = __expf(s[u][v] - mrow[u]);
                pw[u] = p;
                rs[u] += p;
            }
            *(f4*)&PT[((tj << 2) + v) * 68 + ti] = pw;
        }
#pragma unroll
        for (int u = 0; u < 4; ++u) red[(ti + u) * 17 + tj] = rs[u];
        __syncthreads();  // (4)

        if (tid < 64) {
            float st = 0.0f;
#pragma unroll
            for (int t = 0; t < 16; ++t) st += red[tid * 17 + t];
            lsum[tid] = lsum[tid] * alpha_s[tid] + st;
        }

        // rescale O, then O[c][i] += sum_j V^T[c][j] * P^T[j][i]
        f4 al = *(const f4*)&alpha_s[ti];
#pragma unroll
        for (int w = 0; w < 8; ++w)
#pragma unroll
            for (int u = 0; u < 4; ++u) oacc[w][u] *= al[u];

        for (int j4 = 0; j4 < 64; j4 += 4) {
            f4 p0 = *(const f4*)&PT[(j4 + 0) * 68 + ti];
            f4 p1 = *(const f4*)&PT[(j4 + 1) * 68 + ti];
            f4 p2 = *(const f4*)&PT[(j4 + 2) * 68 + ti];
            f4 p3 = *(const f4*)&PT[(j4 + 3) * 68 + ti];
#pragma unroll
            for (int w = 0; w < 8; ++w) {
                f4 vv = *(const f4*)&VsT[(tj + (w << 4)) * 68 + j4];
#pragma unroll
                for (int u = 0; u < 4; ++u)
                    oacc[w][u] += p0[u] * vv[0] + p1[u] * vv[1] + p2[u] * vv[2] + p3[u] * vv[3];
            }
        }
        __syncthreads();  // (5) protects KsT/VsT/red/PT for next tile, lsum for epilogue
    }

    // epilogue: normalize by lsum, write out[b][c][i] (natural layout)
    f4 lv = *(const f4*)&lsum[ti];
    f4 rl;
#pragma unroll
    for (int u = 0; u < 4; ++u) rl[u] = 1.0f / lv[u];
    float* O = out + (size_t)b * CH * NPIX;
#pragma unroll
    for (int w = 0; w < 8; ++w) {
        int c = tj + (w << 4);
        f4 r;
#pragma unroll
        for (int u = 0; u < 4; ++u) r[u] = oacc[w][u] * rl[u];
        *(f4*)&O[c * NPIX + i0g + ti] = r;
    }
}

extern "C" void kernel_launch(void* const* d_in, const int* in_sizes, int n_in,
                              void* d_out, int out_size, void* d_ws, size_t ws_size,
                              hipStream_t stream) {
    const float* x1 = (const float*)d_in[0];
    const float* x2 = (const float*)d_in[1];
    const float* Wq = (const float*)d_in[2];
    const float* bq = (const float*)d_in[3];
    const float* Wk = (const float*)d_in[4];
    const float* bk = (const float*)d_in[5];
    const float* Wv = (const float*)d_in[6];
    const float* bv = (const float*)d_in[7];
    float* outp = (float*)d_out;

    float* qws = (float*)d_ws;
    float* kws = qws + (size_t)BATCH * CH * NPIX;
    float* vws = kws + (size_t)BATCH * CH * NPIX;
    float* wt = vws + (size_t)BATCH * CH * NPIX;  // 3*128*128 floats

    wtrans_kernel<<<3, 256, 0, stream>>>(Wq, Wk, Wv, wt);
    qkv_kernel<<<3 * BATCH * (NPIX / 64), 256, 0, stream>>>(x1, x2, wt, bq, bk, bv, qws, kws, vws);
    attn_kernel<<<BATCH * (NPIX / 64), 256, 0, stream>>>(qws, kws, vws, outp);
}

// Round 2
// 366.326 us; speedup vs baseline: 3.7167x; 3.7167x over previous
//
#include <hip/hip_runtime.h>

typedef float f4 __attribute__((ext_vector_type(4)));
typedef short s8 __attribute__((ext_vector_type(8)));
typedef unsigned short ushort_t;
typedef ushort_t us4 __attribute__((ext_vector_type(4)));
typedef unsigned int uint_t;
typedef uint_t u4 __attribute__((ext_vector_type(4)));

#define BATCH 8
#define CH 128
#define NPIX 4096
#define KSTR 136   // 64-key tile rows, 128 ch + 8 pad (16B-aligned rows, balanced banks)
#define VSTR 72    // 128-ch tile rows, 64 j + 8 pad
#define PSTR 72    // 64-query rows, 64 j + 8 pad (pad doubles as float scratch)

__device__ inline ushort_t f2bf(float f) {   // fp32 -> bf16 RNE (bit pattern)
    uint_t u = __float_as_uint(f);
    u += 0x7fff + ((u >> 16) & 1);
    return (ushort_t)(u >> 16);
}
__device__ inline float bf2f(ushort_t h) { return __uint_as_float(((uint_t)h) << 16); }

__device__ inline f4 mfma16(s8 a, s8 b, f4 c) {
    return __builtin_amdgcn_mfma_f32_16x16x32_bf16(a, b, c, 0, 0, 0);
}

// ---------------- weight transpose: wt[m][c][o] = W_m[o][c] ----------------
__global__ __launch_bounds__(256) void wtrans_kernel(const float* __restrict__ Wq,
                                                     const float* __restrict__ Wk,
                                                     const float* __restrict__ Wv,
                                                     float* __restrict__ wt) {
    int m = blockIdx.x;
    const float* W = (m == 0) ? Wq : (m == 1) ? Wk : Wv;
    float* o = wt + m * CH * CH;
    for (int idx = threadIdx.x; idx < CH * CH; idx += 256) {
        int r = idx >> 7;
        int c = idx & (CH - 1);
        o[c * CH + r] = W[idx];
    }
}

// ---------------- QKV projection -> split bf16 hi/lo ----------------
// Q,K: [b][n][c] (c contiguous);  V: [b][c][n] (n contiguous)
__global__ __launch_bounds__(256) void qkv_kernel(const float* __restrict__ x1,
                                                  const float* __restrict__ x2,
                                                  const float* __restrict__ wt,
                                                  const float* __restrict__ bq,
                                                  const float* __restrict__ bk,
                                                  const float* __restrict__ bv,
                                                  ushort_t* __restrict__ Qh, ushort_t* __restrict__ Ql,
                                                  ushort_t* __restrict__ Kh, ushort_t* __restrict__ Kl,
                                                  ushort_t* __restrict__ Vh, ushort_t* __restrict__ Vl) {
    __shared__ __align__(16) float WTs[CH * CH];
    __shared__ __align__(16) float Xs[CH * 64];

    int bid = blockIdx.x;
    int m = bid >> 9;
    int rem = bid & 511;
    int b = rem & 7;
    int n0 = (rem >> 3) << 6;

    const float* X = ((m == 0) ? x1 : x2) + (size_t)b * CH * NPIX;
    const float* WTm = wt + m * CH * CH;
    const float* bias = (m == 0) ? bq : (m == 1) ? bk : bv;

    int tid = threadIdx.x;
#pragma unroll
    for (int r = 0; r < 16; ++r) {
        int fi = r * 1024 + tid * 4;
        *(f4*)&WTs[fi] = *(const f4*)&WTm[fi];
    }
#pragma unroll
    for (int r = 0; r < 8; ++r) {
        int q4 = r * 256 + tid;
        int c = q4 >> 4;
        int nn = (q4 & 15) << 2;
        *(f4*)&Xs[c * 64 + nn] = *(const f4*)&X[c * NPIX + n0 + nn];
    }
    __syncthreads();

    int to = (tid & 15) << 2;
    int tn = (tid >> 4) << 2;

    float a0[4][4] = {{0.f}}, a1[4][4] = {{0.f}};
#pragma unroll 4
    for (int c = 0; c < CH; ++c) {
        f4 xv = *(const f4*)&Xs[c * 64 + tn];
        f4 w0 = *(const f4*)&WTs[c * CH + to];
        f4 w1 = *(const f4*)&WTs[c * CH + 64 + to];
#pragma unroll
        for (int u = 0; u < 4; ++u)
#pragma unroll
            for (int w = 0; w < 4; ++w) {
                a0[u][w] += w0[u] * xv[w];
                a1[u][w] += w1[u] * xv[w];
            }
    }

    if (m < 2) {  // [b][n][c]
        ushort_t* Yh = (m == 0) ? Qh : Kh;
        ushort_t* Yl = (m == 0) ? Ql : Kl;
#pragma unroll
        for (int w = 0; w < 4; ++w) {
            size_t rowb = ((size_t)b * NPIX + n0 + tn + w) * CH;
            us4 h0, l0, h1, l1;
#pragma unroll
            for (int u = 0; u < 4; ++u) {
                float v0 = a0[u][w] + bias[to + u];
                ushort_t hh = f2bf(v0);
                h0[u] = hh; l0[u] = f2bf(v0 - bf2f(hh));
                float v1 = a1[u][w] + bias[64 + to + u];
                hh = f2bf(v1);
                h1[u] = hh; l1[u] = f2bf(v1 - bf2f(hh));
            }
            *(us4*)&Yh[rowb + to] = h0;
            *(us4*)&Yl[rowb + to] = l0;
            *(us4*)&Yh[rowb + 64 + to] = h1;
            *(us4*)&Yl[rowb + 64 + to] = l1;
        }
    } else {  // V: [b][c][n]
#pragma unroll
        for (int u = 0; u < 4; ++u) {
            int o0 = to + u, o1 = 64 + to + u;
            float bb0 = bias[o0], bb1 = bias[o1];
            us4 h0, l0, h1, l1;
#pragma unroll
            for (int w = 0; w < 4; ++w) {
                float v0 = a0[u][w] + bb0;
                ushort_t hh = f2bf(v0);
                h0[w] = hh; l0[w] = f2bf(v0 - bf2f(hh));
                float v1 = a1[u][w] + bb1;
                hh = f2bf(v1);
                h1[w] = hh; l1[w] = f2bf(v1 - bf2f(hh));
            }
            *(us4*)&Vh[((size_t)b * CH + o0) * NPIX + n0 + tn] = h0;
            *(us4*)&Vl[((size_t)b * CH + o0) * NPIX + n0 + tn] = l0;
            *(us4*)&Vh[((size_t)b * CH + o1) * NPIX + n0 + tn] = h1;
            *(us4*)&Vl[((size_t)b * CH + o1) * NPIX + n0 + tn] = l1;
        }
    }
}

// ---------------- MFMA flash attention (transposed products) ----------------
// grid: 8 * 64 blocks, 256 threads, 80 896 B LDS -> 2 blocks/CU
__global__ __launch_bounds__(256, 2) void attn_kernel(const ushort_t* __restrict__ Qh,
                                                      const ushort_t* __restrict__ Ql,
                                                      const ushort_t* __restrict__ Kh,
                                                      const ushort_t* __restrict__ Kl,
                                                      const ushort_t* __restrict__ Vh,
                                                      const ushort_t* __restrict__ Vl,
                                                      float* __restrict__ out) {
    __shared__ ushort_t sK[2 * 64 * KSTR];   // [split][key][KSTR]
    __shared__ ushort_t sV[2 * 128 * VSTR];  // [split][c][VSTR]
    __shared__ ushort_t sP[64 * PSTR];       // [query][PSTR]; cols 64..71 = 4 floats scratch

    int tid = threadIdx.x;
    int lane = tid & 63;
    int w = tid >> 6;
    int l15 = lane & 15;
    int quad = lane >> 4;

    int b = blockIdx.x & 7;               // batch -> XCD for K/V L2 locality
    int i0g = (blockIdx.x >> 3) << 6;     // query-tile base

    int qbase = (w >> 1) << 5;            // wave query half
    int keybase = (w & 1) << 5;           // wave key half (S)
    int cbase = (w & 1) << 6;             // wave channel half (PV)

    // --- preload Q B-fragments into registers (held for the whole j-loop) ---
    s8 qfh[4][2], qfl[4][2];
#pragma unroll
    for (int qt = 0; qt < 2; ++qt) {
        size_t row = (size_t)b * NPIX + i0g + qbase + qt * 16 + l15;
        const ushort_t* ph = Qh + row * CH + quad * 8;
        const ushort_t* pl = Ql + row * CH + quad * 8;
#pragma unroll
        for (int kc = 0; kc < 4; ++kc) {
            qfh[kc][qt] = *(const s8*)(ph + kc * 32);
            qfl[kc][qt] = *(const s8*)(pl + kc * 32);
        }
    }

    f4 accO[4][2];
#pragma unroll
    for (int ct = 0; ct < 4; ++ct)
#pragma unroll
        for (int qt = 0; qt < 2; ++qt) accO[ct][qt] = f4{0.f, 0.f, 0.f, 0.f};
    float mprev[2] = {-1e30f, -1e30f};
    float lsum[2] = {0.f, 0.f};

    // staging thread mapping
    int kkey = tid >> 4;            // 0..15
    int kc8 = (tid & 15) << 3;      // channel offset 0..120
    int vc = tid >> 3;              // 0..31
    int vj8 = (tid & 7) << 3;       // j offset 0..56

    const ushort_t* Kh_b = Kh + ((size_t)b * NPIX + kkey) * CH + kc8;
    const ushort_t* Kl_b = Kl + ((size_t)b * NPIX + kkey) * CH + kc8;
    const ushort_t* Vh_b = Vh + ((size_t)b * CH + vc) * NPIX + vj8;
    const ushort_t* Vl_b = Vl + ((size_t)b * CH + vc) * NPIX + vj8;

    for (int jt = 0; jt < 64; ++jt) {
        int j0g = jt << 6;
        __syncthreads();  // B0: previous PV reads done; safe to overwrite K/V

        u4 tmp[16];
#pragma unroll
        for (int p = 0; p < 4; ++p) tmp[p] = *(const u4*)(Kh_b + (size_t)(j0g + p * 16) * CH);
#pragma unroll
        for (int p = 0; p < 4; ++p) tmp[4 + p] = *(const u4*)(Kl_b + (size_t)(j0g + p * 16) * CH);
#pragma unroll
        for (int p = 0; p < 4; ++p) tmp[8 + p] = *(const u4*)(Vh_b + (size_t)(p * 32) * NPIX + j0g);
#pragma unroll
        for (int p = 0; p < 4; ++p) tmp[12 + p] = *(const u4*)(Vl_b + (size_t)(p * 32) * NPIX + j0g);
#pragma unroll
        for (int p = 0; p < 4; ++p) *(u4*)&sK[(p * 16 + kkey) * KSTR + kc8] = tmp[p];
#pragma unroll
        for (int p = 0; p < 4; ++p) *(u4*)&sK[64 * KSTR + (p * 16 + kkey) * KSTR + kc8] = tmp[4 + p];
#pragma unroll
        for (int p = 0; p < 4; ++p) *(u4*)&sV[(p * 32 + vc) * VSTR + vj8] = tmp[8 + p];
#pragma unroll
        for (int p = 0; p < 4; ++p) *(u4*)&sV[128 * VSTR + (p * 32 + vc) * VSTR + vj8] = tmp[12 + p];
        __syncthreads();  // B1: tiles staged

        // --- S^T[key][query] = K·Q^T, 3-pass split bf16 ---
        f4 acc[2][2];
#pragma unroll
        for (int kt = 0; kt < 2; ++kt)
#pragma unroll
            for (int qt = 0; qt < 2; ++qt) acc[kt][qt] = f4{0.f, 0.f, 0.f, 0.f};
#pragma unroll
        for (int kc = 0; kc < 4; ++kc) {
            int co = kc * 32 + quad * 8;
            s8 ah0 = *(const s8*)&sK[(keybase + l15) * KSTR + co];
            s8 ah1 = *(const s8*)&sK[(keybase + 16 + l15) * KSTR + co];
            s8 al0 = *(const s8*)&sK[64 * KSTR + (keybase + l15) * KSTR + co];
            s8 al1 = *(const s8*)&sK[64 * KSTR + (keybase + 16 + l15) * KSTR + co];
#pragma unroll
            for (int qt = 0; qt < 2; ++qt) {
                acc[0][qt] = mfma16(ah0, qfh[kc][qt], acc[0][qt]);
                acc[1][qt] = mfma16(ah1, qfh[kc][qt], acc[1][qt]);
                acc[0][qt] = mfma16(ah0, qfl[kc][qt], acc[0][qt]);
                acc[1][qt] = mfma16(ah1, qfl[kc][qt], acc[1][qt]);
                acc[0][qt] = mfma16(al0, qfh[kc][qt], acc[0][qt]);
                acc[1][qt] = mfma16(al1, qfh[kc][qt], acc[1][qt]);
            }
        }

        // --- per-query max over this wave's 32 keys ---
        float pmax[2];
#pragma unroll
        for (int qt = 0; qt < 2; ++qt) {
            float m8 = acc[0][qt][0];
#pragma unroll
            for (int r = 1; r < 4; ++r) m8 = fmaxf(m8, acc[0][qt][r]);
#pragma unroll
            for (int r = 0; r < 4; ++r) m8 = fmaxf(m8, acc[1][qt][r]);
            m8 = fmaxf(m8, __shfl_xor(m8, 16));
            m8 = fmaxf(m8, __shfl_xor(m8, 32));
            pmax[qt] = m8;
        }
        if (lane < 16) {
#pragma unroll
            for (int qt = 0; qt < 2; ++qt)
                ((float*)(sP + (qbase + qt * 16 + lane) * PSTR + 64))[w & 1] = pmax[qt];
        }
        __syncthreads();  // B2: partial maxima visible

        float alpha[2], mnew[2];
#pragma unroll
        for (int qt = 0; qt < 2; ++qt) {
            const float* pr = (const float*)(sP + (qbase + qt * 16 + l15) * PSTR + 64);
            float mt = fmaxf(pr[0], pr[1]);
            mnew[qt] = fmaxf(mprev[qt], mt);
            alpha[qt] = __expf(mprev[qt] - mnew[qt]);
            mprev[qt] = mnew[qt];
        }

        // --- P = exp(S - m), write bf16 to sP, partial row sums ---
        float psum[2] = {0.f, 0.f};
#pragma unroll
        for (int qt = 0; qt < 2; ++qt) {
            int prow = (qbase + qt * 16 + l15) * PSTR;
#pragma unroll
            for (int kt = 0; kt < 2; ++kt)
#pragma unroll
                for (int r = 0; r < 4; ++r) {
                    float p = __expf(acc[kt][qt][r] - mnew[qt]);
                    psum[qt] += p;
                    sP[prow + keybase + kt * 16 + quad * 4 + r] = f2bf(p);
                }
            psum[qt] += __shfl_xor(psum[qt], 16);
            psum[qt] += __shfl_xor(psum[qt], 32);
        }
        if (lane < 16) {
#pragma unroll
            for (int qt = 0; qt < 2; ++qt)
                ((float*)(sP + (qbase + qt * 16 + lane) * PSTR + 64))[2 + (w & 1)] = psum[qt];
        }
        __syncthreads();  // B3: P + partial sums visible

#pragma unroll
        for (int qt = 0; qt < 2; ++qt) {
            const float* pr = (const float*)(sP + (qbase + qt * 16 + l15) * PSTR + 64);
            lsum[qt] = lsum[qt] * alpha[qt] + pr[2] + pr[3];
#pragma unroll
            for (int ct = 0; ct < 4; ++ct)
#pragma unroll
                for (int r = 0; r < 4; ++r) accO[ct][qt][r] *= alpha[qt];
        }

        // --- O^T[c][i] += V-as-A · P-as-B, 2-pass (V split, P hi only) ---
#pragma unroll
        for (int kc2 = 0; kc2 < 2; ++kc2) {
            int jo = kc2 * 32 + quad * 8;
            s8 bp[2];
#pragma unroll
            for (int qt = 0; qt < 2; ++qt)
                bp[qt] = *(const s8*)&sP[(qbase + qt * 16 + l15) * PSTR + jo];
#pragma unroll
            for (int ct = 0; ct < 4; ++ct) {
                s8 vh = *(const s8*)&sV[(cbase + ct * 16 + l15) * VSTR + jo];
                s8 vl = *(const s8*)&sV[128 * VSTR + (cbase + ct * 16 + l15) * VSTR + jo];
#pragma unroll
                for (int qt = 0; qt < 2; ++qt) {
                    accO[ct][qt] = mfma16(vh, bp[qt], accO[ct][qt]);
                    accO[ct][qt] = mfma16(vl, bp[qt], accO[ct][qt]);
                }
            }
        }
    }

    // --- epilogue: normalize, coalesced store out[b][c][i] ---
    float li[2] = {1.0f / lsum[0], 1.0f / lsum[1]};
    float* O = out + (size_t)b * CH * NPIX;
#pragma unroll
    for (int ct = 0; ct < 4; ++ct)
#pragma unroll
        for (int qt = 0; qt < 2; ++qt) {
            int i = i0g + qbase + qt * 16 + l15;
#pragma unroll
            for (int r = 0; r < 4; ++r) {
                int c = cbase + ct * 16 + quad * 4 + r;
                O[(size_t)c * NPIX + i] = accO[ct][qt][r] * li[qt];
            }
        }
}

extern "C" void kernel_launch(void* const* d_in, const int* in_sizes, int n_in,
                              void* d_out, int out_size, void* d_ws, size_t ws_size,
                              hipStream_t stream) {
    const float* x1 = (const float*)d_in[0];
    const float* x2 = (const float*)d_in[1];
    const float* Wq = (const float*)d_in[2];
    const float* bq = (const float*)d_in[3];
    const float* Wk = (const float*)d_in[4];
    const float* bk = (const float*)d_in[5];
    const float* Wv = (const float*)d_in[6];
    const float* bv = (const float*)d_in[7];
    float* outp = (float*)d_out;

    const size_t N = (size_t)BATCH * NPIX * CH;
    ushort_t* Qh = (ushort_t*)d_ws;
    ushort_t* Ql = Qh + N;
    ushort_t* Kh = Qh + 2 * N;
    ushort_t* Kl = Qh + 3 * N;
    ushort_t* Vh = Qh + 4 * N;
    ushort_t* Vl = Qh + 5 * N;
    float* wt = (float*)(Qh + 6 * N);

    wtrans_kernel<<<3, 256, 0, stream>>>(Wq, Wk, Wv, wt);
    qkv_kernel<<<3 * BATCH * (NPIX / 64), 256, 0, stream>>>(x1, x2, wt, bq, bk, bv,
                                                            Qh, Ql, Kh, Kl, Vh, Vl);
    attn_kernel<<<BATCH * (NPIX / 64), 256, 0, stream>>>(Qh, Ql, Kh, Kl, Vh, Vl, outp);
}

// Round 3
// 313.434 us; speedup vs baseline: 4.3439x; 1.1688x over previous
//
#include <hip/hip_runtime.h>

typedef float f4 __attribute__((ext_vector_type(4)));
typedef float f16v __attribute__((ext_vector_type(16)));
typedef short s8 __attribute__((ext_vector_type(8)));
typedef unsigned short ushort_t;
typedef ushort_t us4 __attribute__((ext_vector_type(4)));
typedef unsigned int uint_t;
typedef uint_t u2 __attribute__((ext_vector_type(2)));

#define BATCH 8
#define CH 128
#define NPIX 4096

__device__ inline ushort_t f2bf(float f) {  // fp32 -> bf16 RNE
    uint_t u = __float_as_uint(f);
    u += 0x7fff + ((u >> 16) & 1);
    return (ushort_t)(u >> 16);
}
__device__ inline float bf2f(ushort_t h) { return __uint_as_float(((uint_t)h) << 16); }

__device__ inline f16v mfma32(s8 a, s8 b, f16v c) {
    return __builtin_amdgcn_mfma_f32_32x32x16_bf16(a, b, c, 0, 0, 0);
}

typedef __attribute__((address_space(3))) uint_t lds_uint;
typedef __attribute__((address_space(1))) const uint_t global_uint;
__device__ inline void dma16(const void* g, void* l) {
    // async global->LDS, 16B/lane; LDS dest = wave-uniform base + lane*16
    __builtin_amdgcn_global_load_lds((global_uint*)g, (lds_uint*)l, 16, 0, 0);
}

// ---------------- weight transpose: wt[m][c][o] = W_m[o][c] ----------------
__global__ __launch_bounds__(256) void wtrans_kernel(const float* __restrict__ Wq,
                                                     const float* __restrict__ Wk,
                                                     const float* __restrict__ Wv,
                                                     float* __restrict__ wt) {
    int m = blockIdx.x;
    const float* W = (m == 0) ? Wq : (m == 1) ? Wk : Wv;
    float* o = wt + m * CH * CH;
    for (int idx = threadIdx.x; idx < CH * CH; idx += 256) {
        int r = idx >> 7;
        int c = idx & (CH - 1);
        o[c * CH + r] = W[idx];
    }
}

// ---------------- QKV projection -> split bf16 ----------------
// Q,K: [b][n][c] hi/lo;  V: [b][c][n] hi only.
// grid: 3 * 8 * 32 blocks (128-pixel chunks), 256 threads, 8x8 thread tile.
__global__ __launch_bounds__(256) void qkv_kernel(const float* __restrict__ x1,
                                                  const float* __restrict__ x2,
                                                  const float* __restrict__ wt,
                                                  const float* __restrict__ bq,
                                                  const float* __restrict__ bk,
                                                  const float* __restrict__ bv,
                                                  ushort_t* __restrict__ Qh, ushort_t* __restrict__ Ql,
                                                  ushort_t* __restrict__ Kh, ushort_t* __restrict__ Kl,
                                                  ushort_t* __restrict__ Vh) {
    __shared__ __align__(16) float WTs[CH * 132];  // WT[c][o], stride 132 (2-way banks only)
    __shared__ __align__(16) float Xs[CH * 128];   // X[c][px]

    int bid = blockIdx.x;
    int m = bid >> 8;
    int rem = bid & 255;
    int b = rem & 7;
    int n0 = (rem >> 3) << 7;

    const float* X = ((m == 0) ? x1 : x2) + (size_t)b * CH * NPIX;
    const float* WTm = wt + m * CH * CH;
    const float* bias = (m == 0) ? bq : (m == 1) ? bk : bv;

    int tid = threadIdx.x;
#pragma unroll
    for (int r = 0; r < 16; ++r) {
        int fi = r * 1024 + tid * 4;
        int c = fi >> 7, o = fi & 127;
        *(f4*)&WTs[c * 132 + o] = *(const f4*)&WTm[fi];
        *(f4*)&Xs[c * 128 + o] = *(const f4*)&X[(size_t)c * NPIX + n0 + o];
    }
    __syncthreads();

    int tx = tid & 15, ty = tid >> 4;
    f4 acc[2][2][4];
#pragma unroll
    for (int oi = 0; oi < 2; ++oi)
#pragma unroll
        for (int pi = 0; pi < 2; ++pi)
#pragma unroll
            for (int u = 0; u < 4; ++u) acc[oi][pi][u] = f4{0.f, 0.f, 0.f, 0.f};

#pragma unroll 2
    for (int c = 0; c < CH; ++c) {
        f4 w0 = *(const f4*)&WTs[c * 132 + 4 * ty];
        f4 w1 = *(const f4*)&WTs[c * 132 + 64 + 4 * ty];
        f4 x0 = *(const f4*)&Xs[c * 128 + 4 * tx];
        f4 x1v = *(const f4*)&Xs[c * 128 + 64 + 4 * tx];
#pragma unroll
        for (int u = 0; u < 4; ++u) {
            acc[0][0][u] += w0[u] * x0;
            acc[0][1][u] += w0[u] * x1v;
            acc[1][0][u] += w1[u] * x0;
            acc[1][1][u] += w1[u] * x1v;
        }
    }

    if (m < 2) {  // Q/K -> [b][n][c] hi/lo
        ushort_t* Yh = (m == 0) ? Qh : Kh;
        ushort_t* Yl = (m == 0) ? Ql : Kl;
#pragma unroll
        for (int pi = 0; pi < 2; ++pi)
#pragma unroll
            for (int pp = 0; pp < 4; ++pp) {
                size_t rowb = ((size_t)b * NPIX + n0 + pi * 64 + 4 * tx + pp) * CH;
#pragma unroll
                for (int oi = 0; oi < 2; ++oi) {
                    us4 hh, ll;
#pragma unroll
                    for (int u = 0; u < 4; ++u) {
                        float v = acc[oi][pi][u][pp] + bias[oi * 64 + 4 * ty + u];
                        ushort_t hb = f2bf(v);
                        hh[u] = hb;
                        ll[u] = f2bf(v - bf2f(hb));
                    }
                    *(us4*)&Yh[rowb + oi * 64 + 4 * ty] = hh;
                    *(us4*)&Yl[rowb + oi * 64 + 4 * ty] = ll;
                }
            }
    } else {  // V -> [b][c][n] hi only
#pragma unroll
        for (int oi = 0; oi < 2; ++oi)
#pragma unroll
            for (int u = 0; u < 4; ++u) {
                int ch = oi * 64 + 4 * ty + u;
                float bb = bias[ch];
#pragma unroll
                for (int pi = 0; pi < 2; ++pi) {
                    us4 hv;
#pragma unroll
                    for (int pp = 0; pp < 4; ++pp) hv[pp] = f2bf(acc[oi][pi][u][pp] + bb);
                    *(us4*)&Vh[((size_t)b * CH + ch) * NPIX + n0 + pi * 64 + 4 * tx] = hv;
                }
            }
    }
}

// ---------------- MFMA flash attention, 32x32 tiles, wave-private softmax ----------------
// grid: 8 * 64 blocks, 256 threads (4 waves = 2 query-halves x 2 key-halves)
// LDS 72 KB -> 2 blocks/CU. All layouts XOR-swizzled (no pad) for global_load_lds.
__global__ __launch_bounds__(256, 2) void attn_kernel(const ushort_t* __restrict__ Qh,
                                                      const ushort_t* __restrict__ Ql,
                                                      const ushort_t* __restrict__ Kh,
                                                      const ushort_t* __restrict__ Kl,
                                                      const ushort_t* __restrict__ Vh,
                                                      float* __restrict__ out) {
    __shared__ __align__(16) ushort_t smem[36864];  // 72 KB
    ushort_t* sKh = smem;          // 64 keys x 128ch, swizzle chunk^=(row&15)
    ushort_t* sKl = smem + 8192;
    ushort_t* sV = smem + 16384;   // 2 x (128ch x 64j), swizzle chunk^=(row&7)
    ushort_t* sP = smem + 32768;   // 64q x 64k, swizzle 16B-chunk^=(row&7); wave-private quadrants

    int tid = threadIdx.x;
    int lane = tid & 63;
    int w = tid >> 6;
    int h = lane >> 5;
    int m32 = lane & 31;
    int qh = w >> 1, kh = w & 1;

    int b = blockIdx.x & 7;            // batch <-> XCD for K/V L2 locality
    int i0g = (blockIdx.x >> 3) << 6;  // 64-query tile
    int qrow = i0g + qh * 32 + m32;

    const ushort_t* Qhb = Qh + (size_t)b * NPIX * CH;
    const ushort_t* Qlb = Ql + (size_t)b * NPIX * CH;
    const ushort_t* Khb = Kh + (size_t)b * NPIX * CH;
    const ushort_t* Klb = Kl + (size_t)b * NPIX * CH;
    const ushort_t* Vhb = Vh + (size_t)b * CH * NPIX;

    // Q B-frags in registers for the whole loop (B[n=m32][k=h*8+j], per 16-ch slab)
    s8 qfh[8], qfl[8];
#pragma unroll
    for (int kc = 0; kc < 8; ++kc) {
        size_t off = (size_t)qrow * CH + kc * 16 + h * 8;
        qfh[kc] = *(const s8*)&Qhb[off];
        qfl[kc] = *(const s8*)&Qlb[off];
    }

    // DMA source pointers (per-lane, swizzle folded into global address), tile 0
    const ushort_t* pK[4];
    const ushort_t* pKl_[4];
    const ushort_t* pV[4];
#pragma unroll
    for (int a = 0; a < 4; ++a) {
        int g = w * 4 + a;
        int rowk = g * 4 + (lane >> 4);               // sK: 4 key-rows per 1KB inst
        int lck = (lane & 15) ^ (rowk & 15);
        pK[a] = Khb + (size_t)rowk * CH + lck * 8;
        pKl_[a] = Klb + (size_t)rowk * CH + lck * 8;
        int rowv = g * 8 + (lane >> 3);               // sV: 8 ch-rows per 1KB inst
        int lcv = (lane & 7) ^ (rowv & 7);
        pV[a] = Vhb + (size_t)rowv * NPIX + lcv * 8;
    }

    // prologue: stage tile 0 (K hi/lo + V buf0), advance to tile 1
#pragma unroll
    for (int a = 0; a < 4; ++a) {
        dma16(pK[a], &sKh[(w * 4 + a) * 512]);
        dma16(pKl_[a], &sKl[(w * 4 + a) * 512]);
        dma16(pV[a], &sV[(w * 4 + a) * 512]);
        pK[a] += 64 * CH;
        pKl_[a] += 64 * CH;
        pV[a] += 64;
    }

    f16v accO[4];
#pragma unroll
    for (int ct = 0; ct < 4; ++ct)
#pragma unroll
        for (int r = 0; r < 16; ++r) accO[ct][r] = 0.f;
    float mprev = -1e30f, lsum = 0.f;

    __syncthreads();  // tile-0 staged

    for (int t = 0; t < 64; ++t) {
        int cur = t & 1;
        // prefetch V(t+1) into the other buffer (flight covers the whole S phase)
        if (t < 63) {
#pragma unroll
            for (int a = 0; a < 4; ++a) {
                dma16(pV[a], &sV[(1 - cur) * 8192 + (w * 4 + a) * 512]);
                pV[a] += 64;
            }
        }

        // --- S^T[key][query] = K . Q^T, 3-pass split bf16 (hh + h.l + l.h) ---
        f16v acc;
#pragma unroll
        for (int r = 0; r < 16; ++r) acc[r] = 0.f;
        int krow = kh * 32 + m32;
#pragma unroll
        for (int kc = 0; kc < 8; ++kc) {
            int pA = (kc * 2 + h) ^ (m32 & 15);
            s8 ahi = *(const s8*)&sKh[krow * 128 + pA * 8];
            s8 alo = *(const s8*)&sKl[krow * 128 + pA * 8];
            acc = mfma32(ahi, qfh[kc], acc);
            acc = mfma32(ahi, qfl[kc], acc);
            acc = mfma32(alo, qfh[kc], acc);
        }

        // --- wave-private online softmax over this wave's 32 keys ---
        float tmax = acc[0];
#pragma unroll
        for (int r = 1; r < 16; ++r) tmax = fmaxf(tmax, acc[r]);
        tmax = fmaxf(tmax, __shfl_xor(tmax, 32));
        float mnew = fmaxf(mprev, tmax);
        if (__any(tmax > mprev)) {  // skip rescale when no row raised its max
            float alpha = __expf(mprev - mnew);
            lsum *= alpha;
#pragma unroll
            for (int ct = 0; ct < 4; ++ct)
#pragma unroll
                for (int r = 0; r < 16; ++r) accO[ct][r] *= alpha;
        }
        mprev = mnew;

        float psum = 0.f;
        uint_t ub[16];
#pragma unroll
        for (int r = 0; r < 16; ++r) {
            float p = __expf(acc[r] - mnew);
            uint_t u = __float_as_uint(p) & 0xffff0000u;  // truncate; psum uses SAME value
            psum += __uint_as_float(u);
            ub[r] = u;
        }
        int prow = (qh * 32 + m32) * 64;
#pragma unroll
        for (int g = 0; g < 4; ++g) {  // keys 8g+4h..+3 -> one b64 store
            u2 d;
            d[0] = (ub[4 * g] >> 16) | ub[4 * g + 1];
            d[1] = (ub[4 * g + 2] >> 16) | ub[4 * g + 3];
            int pc = (kh * 4 + g) ^ (m32 & 7);
            *(u2*)&sP[prow + pc * 8 + h * 4] = d;
        }
        psum += __shfl_xor(psum, 32);
        lsum += psum;

        __syncthreads();  // B_mid: all waves done reading sK(t); drains V(t+1) DMA

        // stage K(t+1) now; flight overlaps PV below
        if (t < 63) {
#pragma unroll
            for (int a = 0; a < 4; ++a) {
                dma16(pK[a], &sKh[(w * 4 + a) * 512]);
                dma16(pKl_[a], &sKl[(w * 4 + a) * 512]);
                pK[a] += 64 * CH;
                pKl_[a] += 64 * CH;
            }
        }

        // --- O^T[c][q] += V . P (wave's own 32-key half, all 128 channels) ---
        const ushort_t* sVc = sV + cur * 8192;
#pragma unroll
        for (int kc2 = 0; kc2 < 2; ++kc2) {
            int pc2 = (kh * 4 + kc2 * 2 + h) ^ (m32 & 7);
            s8 bp = *(const s8*)&sP[prow + pc2 * 8];
#pragma unroll
            for (int ct = 0; ct < 4; ++ct) {
                s8 av = *(const s8*)&sVc[(ct * 32 + m32) * 64 + pc2 * 8];
                accO[ct] = mfma32(av, bp, accO[ct]);
            }
        }

        __syncthreads();  // B_end: drains K(t+1) DMA; PV reads done before V-buf reuse
    }

    // --- epilogue: flash combine of the two key-half waves, then store ---
    __syncthreads();
    float* scr = (float*)sP;
    if (h == 0) {
        scr[kh * 64 + qh * 32 + m32] = mprev;
        scr[128 + kh * 64 + qh * 32 + m32] = lsum;
    }
    __syncthreads();
    float mo = scr[(1 - kh) * 64 + qh * 32 + m32];
    float lo2 = scr[128 + (1 - kh) * 64 + qh * 32 + m32];
    float mf = fmaxf(mprev, mo);
    float fs = __expf(mprev - mf);
    float fo = __expf(mo - mf);
    float rinv = fs / (fs * lsum + fo * lo2);

    float* mrg = (float*)smem;  // reuse sK region (32 KB = 8192 floats)
    if (kh == 1) {
#pragma unroll
        for (int ct = 0; ct < 4; ++ct)
#pragma unroll
            for (int r = 0; r < 16; ++r) {
                int ch = ct * 32 + (r & 3) + 8 * (r >> 2) + 4 * h;
                mrg[qh * 4096 + ch * 32 + m32] = accO[ct][r] * rinv;
            }
    }
    __syncthreads();
    if (kh == 0) {
        float* O = out + (size_t)b * CH * NPIX;
#pragma unroll
        for (int ct = 0; ct < 4; ++ct)
#pragma unroll
            for (int r = 0; r < 16; ++r) {
                int ch = ct * 32 + (r & 3) + 8 * (r >> 2) + 4 * h;
                O[(size_t)ch * NPIX + i0g + qh * 32 + m32] =
                    accO[ct][r] * rinv + mrg[qh * 4096 + ch * 32 + m32];
            }
    }
}

extern "C" void kernel_launch(void* const* d_in, const int* in_sizes, int n_in,
                              void* d_out, int out_size, void* d_ws, size_t ws_size,
                              hipStream_t stream) {
    const float* x1 = (const float*)d_in[0];
    const float* x2 = (const float*)d_in[1];
    const float* Wq = (const float*)d_in[2];
    const float* bq = (const float*)d_in[3];
    const float* Wk = (const float*)d_in[4];
    const float* bk = (const float*)d_in[5];
    const float* Wv = (const float*)d_in[6];
    const float* bv = (const float*)d_in[7];
    float* outp = (float*)d_out;

    const size_t N = (size_t)BATCH * NPIX * CH;
    ushort_t* Qh = (ushort_t*)d_ws;
    ushort_t* Ql = Qh + N;
    ushort_t* Kh = Qh + 2 * N;
    ushort_t* Kl = Qh + 3 * N;
    ushort_t* Vh = Qh + 4 * N;
    float* wt = (float*)(Qh + 5 * N);

    wtrans_kernel<<<3, 256, 0, stream>>>(Wq, Wk, Wv, wt);
    qkv_kernel<<<3 * BATCH * (NPIX / 128), 256, 0, stream>>>(x1, x2, wt, bq, bk, bv,
                                                             Qh, Ql, Kh, Kl, Vh);
    attn_kernel<<<BATCH * (NPIX / 64), 256, 0, stream>>>(Qh, Ql, Kh, Kl, Vh, outp);
}

// Round 5
// 268.096 us; speedup vs baseline: 5.0785x; 1.1691x over previous
//
#include <hip/hip_runtime.h>

typedef float f4 __attribute__((ext_vector_type(4)));
typedef float f16v __attribute__((ext_vector_type(16)));
typedef _Float16 hf;
typedef __fp16 fp16x2 __attribute__((ext_vector_type(2)));
typedef hf h4 __attribute__((ext_vector_type(4)));
typedef hf h8 __attribute__((ext_vector_type(8)));
typedef unsigned short ushort_t;
typedef unsigned int uint_t;
typedef uint_t u4 __attribute__((ext_vector_type(4)));

#define BATCH 8
#define CH 128
#define NPIX 4096

__device__ inline f16v mfma32h(h8 a, h8 b, f16v c) {
    return __builtin_amdgcn_mfma_f32_32x32x16_f16(a, b, c, 0, 0, 0);
}

__device__ inline uint_t pk2h(float a, float b) {  // pack 2 fp32 -> fp16x2 (RTZ), as u32
    fp16x2 pp = __builtin_amdgcn_cvt_pkrtz(a, b);
    union { fp16x2 v; uint_t u; } cv;
    cv.v = pp;
    return cv.u;
}

typedef __attribute__((address_space(3))) uint_t lds_uint;
typedef __attribute__((address_space(1))) const uint_t global_uint;
__device__ inline void dma16(const void* g, void* l) {
    // async global->LDS, 16B/lane; LDS dest = wave-uniform base + lane*16
    __builtin_amdgcn_global_load_lds((global_uint*)g, (lds_uint*)l, 16, 0, 0);
}

// ---------------- weight transpose: wt[m][c][o] = W_m[o][c] ----------------
__global__ __launch_bounds__(256) void wtrans_kernel(const float* __restrict__ Wq,
                                                     const float* __restrict__ Wk,
                                                     const float* __restrict__ Wv,
                                                     float* __restrict__ wt) {
    int m = blockIdx.x;
    const float* W = (m == 0) ? Wq : (m == 1) ? Wk : Wv;
    float* o = wt + m * CH * CH;
    for (int idx = threadIdx.x; idx < CH * CH; idx += 256) {
        int r = idx >> 7;
        int c = idx & (CH - 1);
        o[c * CH + r] = W[idx];
    }
}

// ---------------- QKV projection -> fp16 ----------------
// Q: [b][n][c] hi+lo fp16;  K: [b][n][c] fp16;  V: [b][c][n] fp16.
__global__ __launch_bounds__(256) void qkv_kernel(const float* __restrict__ x1,
                                                  const float* __restrict__ x2,
                                                  const float* __restrict__ wt,
                                                  const float* __restrict__ bq,
                                                  const float* __restrict__ bk,
                                                  const float* __restrict__ bv,
                                                  hf* __restrict__ Qhi, hf* __restrict__ Qlo,
                                                  hf* __restrict__ Kf, hf* __restrict__ Vf) {
    __shared__ __align__(16) float WTs[CH * 132];
    __shared__ __align__(16) float Xs[CH * 128];

    int bid = blockIdx.x;
    int m = bid >> 8;
    int rem = bid & 255;
    int b = rem & 7;
    int n0 = (rem >> 3) << 7;

    const float* X = ((m == 0) ? x1 : x2) + (size_t)b * CH * NPIX;
    const float* WTm = wt + m * CH * CH;
    const float* bias = (m == 0) ? bq : (m == 1) ? bk : bv;

    int tid = threadIdx.x;
#pragma unroll
    for (int r = 0; r < 16; ++r) {
        int fi = r * 1024 + tid * 4;
        int c = fi >> 7, o = fi & 127;
        *(f4*)&WTs[c * 132 + o] = *(const f4*)&WTm[fi];
        *(f4*)&Xs[c * 128 + o] = *(const f4*)&X[(size_t)c * NPIX + n0 + o];
    }
    __syncthreads();

    int tx = tid & 15, ty = tid >> 4;
    f4 acc[2][2][4];
#pragma unroll
    for (int oi = 0; oi < 2; ++oi)
#pragma unroll
        for (int pi = 0; pi < 2; ++pi)
#pragma unroll
            for (int u = 0; u < 4; ++u) acc[oi][pi][u] = f4{0.f, 0.f, 0.f, 0.f};

#pragma unroll 2
    for (int c = 0; c < CH; ++c) {
        f4 w0 = *(const f4*)&WTs[c * 132 + 4 * ty];
        f4 w1 = *(const f4*)&WTs[c * 132 + 64 + 4 * ty];
        f4 x0 = *(const f4*)&Xs[c * 128 + 4 * tx];
        f4 x1v = *(const f4*)&Xs[c * 128 + 64 + 4 * tx];
#pragma unroll
        for (int u = 0; u < 4; ++u) {
            acc[0][0][u] += w0[u] * x0;
            acc[0][1][u] += w0[u] * x1v;
            acc[1][0][u] += w1[u] * x0;
            acc[1][1][u] += w1[u] * x1v;
        }
    }

    if (m == 0) {  // Q -> [b][n][c] hi+lo
#pragma unroll
        for (int pi = 0; pi < 2; ++pi)
#pragma unroll
            for (int pp = 0; pp < 4; ++pp) {
                size_t rowb = ((size_t)b * NPIX + n0 + pi * 64 + 4 * tx + pp) * CH;
#pragma unroll
                for (int oi = 0; oi < 2; ++oi) {
                    h4 hh, ll;
#pragma unroll
                    for (int u = 0; u < 4; ++u) {
                        float v = acc[oi][pi][u][pp] + bias[oi * 64 + 4 * ty + u];
                        hf hb = (hf)v;
                        hh[u] = hb;
                        ll[u] = (hf)(v - (float)hb);
                    }
                    *(h4*)&Qhi[rowb + oi * 64 + 4 * ty] = hh;
                    *(h4*)&Qlo[rowb + oi * 64 + 4 * ty] = ll;
                }
            }
    } else if (m == 1) {  // K -> [b][n][c]
#pragma unroll
        for (int pi = 0; pi < 2; ++pi)
#pragma unroll
            for (int pp = 0; pp < 4; ++pp) {
                size_t rowb = ((size_t)b * NPIX + n0 + pi * 64 + 4 * tx + pp) * CH;
#pragma unroll
                for (int oi = 0; oi < 2; ++oi) {
                    h4 hh;
#pragma unroll
                    for (int u = 0; u < 4; ++u)
                        hh[u] = (hf)(acc[oi][pi][u][pp] + bias[oi * 64 + 4 * ty + u]);
                    *(h4*)&Kf[rowb + oi * 64 + 4 * ty] = hh;
                }
            }
    } else {  // V -> [b][c][n]
#pragma unroll
        for (int oi = 0; oi < 2; ++oi)
#pragma unroll
            for (int u = 0; u < 4; ++u) {
                int ch = oi * 64 + 4 * ty + u;
                float bb = bias[ch];
#pragma unroll
                for (int pi = 0; pi < 2; ++pi) {
                    h4 hv;
#pragma unroll
                    for (int pp = 0; pp < 4; ++pp) hv[pp] = (hf)(acc[oi][pi][u][pp] + bb);
                    *(h4*)&Vf[((size_t)b * CH + ch) * NPIX + n0 + pi * 64 + 4 * tx] = hv;
                }
            }
    }
}

// ---------------- fp16 MFMA flash attention, P-in-registers, 1 barrier/iter ----------------
// grid: 8 * 64 blocks, 256 threads (2 query-halves x 2 key-halves)
// LDS 64 KB (K,V double-buffered) -> 2 blocks/CU.
__global__ __launch_bounds__(256, 2) void attn_kernel(const hf* __restrict__ Qhi,
                                                      const hf* __restrict__ Qlo,
                                                      const hf* __restrict__ Kf,
                                                      const hf* __restrict__ Vf,
                                                      float* __restrict__ out) {
    __shared__ __align__(16) ushort_t smem[32768];  // 64 KB: K buf0/buf1 @0/8192, V buf0/buf1 @16384/24576

    int tid = threadIdx.x;
    int lane = tid & 63;
    int w = tid >> 6;
    int h = lane >> 5;
    int m32 = lane & 31;
    int qh = w >> 1, kh = w & 1;

    int b = blockIdx.x & 7;            // batch <-> XCD for K/V L2 locality
    int i0g = (blockIdx.x >> 3) << 6;  // 64-query tile
    int qrow = i0g + qh * 32 + m32;

    const hf* Qhb = Qhi + (size_t)b * NPIX * CH;
    const hf* Qlb = Qlo + (size_t)b * NPIX * CH;
    const hf* Kfb = Kf + (size_t)b * NPIX * CH;
    const hf* Vfb = Vf + (size_t)b * CH * NPIX;

    // Q B-frags (hi+lo) in registers for the whole loop
    h8 qfh[8], qfl[8];
#pragma unroll
    for (int kc = 0; kc < 8; ++kc) {
        size_t off = (size_t)qrow * CH + kc * 16 + h * 8;
        qfh[kc] = *(const h8*)&Qhb[off];
        qfl[kc] = *(const h8*)&Qlb[off];
    }

    // DMA source pointers (swizzle folded into global address)
    const hf* pK[4];
    const hf* pV[4];
#pragma unroll
    for (int a = 0; a < 4; ++a) {
        int g = w * 4 + a;
        int rowk = g * 4 + (lane >> 4);   // K: 4 key-rows per 1KB chunk (row = 256B)
        int lck = (lane & 15) ^ (rowk & 15);
        pK[a] = Kfb + (size_t)rowk * CH + lck * 8;
        int rowv = g * 8 + (lane >> 3);   // V: 8 ch-rows per 1KB chunk (row = 128B)
        int lcv = (lane & 7) ^ (rowv & 7);
        pV[a] = Vfb + (size_t)rowv * NPIX + lcv * 8;
    }

    // prologue: tile 0 -> buf 0
#pragma unroll
    for (int a = 0; a < 4; ++a) {
        dma16(pK[a], &smem[(w * 4 + a) * 512]);
        dma16(pV[a], &smem[16384 + (w * 4 + a) * 512]);
        pK[a] += 64 * CH;
        pV[a] += 64;
    }

    f16v accO[4];
#pragma unroll
    for (int ct = 0; ct < 4; ++ct)
#pragma unroll
        for (int r = 0; r < 16; ++r) accO[ct][r] = 0.f;
    float mprev = -1e30f, lsum = 0.f;

    __syncthreads();  // tile-0 staged

    for (int t = 0; t < 64; ++t) {
        int cur = t & 1;
        // prefetch tile t+1 into the other buffers; flight covers this whole iter
        if (t < 63) {
            int nb = 1 - cur;
#pragma unroll
            for (int a = 0; a < 4; ++a) {
                dma16(pK[a], &smem[nb * 8192 + (w * 4 + a) * 512]);
                dma16(pV[a], &smem[16384 + nb * 8192 + (w * 4 + a) * 512]);
                pK[a] += 64 * CH;
                pV[a] += 64;
            }
        }
        const ushort_t* kb = smem + cur * 8192;
        const ushort_t* vb = smem + 16384 + cur * 8192;

        // --- S^T[key][query] = K . (Qh+Ql)^T, 2-pass fp16 ---
        f16v acc;
#pragma unroll
        for (int r = 0; r < 16; ++r) acc[r] = 0.f;
        int krow = kh * 32 + m32;
#pragma unroll
        for (int kc = 0; kc < 8; ++kc) {
            int pA = (kc * 2 + h) ^ (m32 & 15);
            h8 ahi = *(const h8*)&kb[krow * 128 + pA * 8];
            acc = mfma32h(ahi, qfh[kc], acc);
            acc = mfma32h(ahi, qfl[kc], acc);
        }

        // --- wave-private online softmax (32 keys) ---
        float tmax = acc[0];
#pragma unroll
        for (int r = 1; r < 16; ++r) tmax = fmaxf(tmax, acc[r]);
        tmax = fmaxf(tmax, __shfl_xor(tmax, 32));
        float mnew = fmaxf(mprev, tmax);
        if (__any(tmax > mprev)) {
            float alpha = __expf(mprev - mnew);
            lsum *= alpha;
#pragma unroll
            for (int ct = 0; ct < 4; ++ct)
#pragma unroll
                for (int r = 0; r < 16; ++r) accO[ct][r] *= alpha;
        }
        mprev = mnew;

        float p[16];
        float psum = 0.f;
#pragma unroll
        for (int r = 0; r < 16; ++r) {
            p[r] = __expf(acc[r] - mnew);
            psum += p[r];
        }
        psum += __shfl_xor(psum, 32);
        lsum += psum;

        // --- pack P to fp16 and build PV B-frags in-register (lane<->lane^32 exchange) ---
        uint_t pk[8], rv[8];
#pragma unroll
        for (int t2 = 0; t2 < 8; ++t2) pk[t2] = pk2h(p[2 * t2], p[2 * t2 + 1]);
#pragma unroll
        for (int t2 = 0; t2 < 8; ++t2) rv[t2] = (uint_t)__shfl_xor((int)pk[t2], 32);

        // --- O^T[c][q] += V . P over this wave's 32 keys ---
#pragma unroll
        for (int g2 = 0; g2 < 2; ++g2) {
            u4 fv;
            fv[0] = h ? rv[g2 * 4 + 2] : pk[g2 * 4 + 0];
            fv[1] = h ? rv[g2 * 4 + 3] : pk[g2 * 4 + 1];
            fv[2] = h ? pk[g2 * 4 + 2] : rv[g2 * 4 + 0];
            fv[3] = h ? pk[g2 * 4 + 3] : rv[g2 * 4 + 1];
            h8 bp;
            __builtin_memcpy(&bp, &fv, 16);
            int pc2 = (kh * 4 + g2 * 2 + h) ^ (m32 & 7);
#pragma unroll
            for (int ct = 0; ct < 4; ++ct) {
                h8 av = *(const h8*)&vb[(ct * 32 + m32) * 64 + pc2 * 8];
                accO[ct] = mfma32h(av, bp, accO[ct]);
            }
        }

        __syncthreads();  // single barrier: drains DMA(t+1); all reads of tile t done
    }

    // --- epilogue: merge the two key-half waves, store out[b][c][i] ---
    float* scr = (float*)smem;  // loop done; smem reusable
    if (h == 0) {
        scr[kh * 64 + qh * 32 + m32] = mprev;
        scr[128 + kh * 64 + qh * 32 + m32] = lsum;
    }
    __syncthreads();
    float mo = scr[(1 - kh) * 64 + qh * 32 + m32];
    float lo2 = scr[128 + (1 - kh) * 64 + qh * 32 + m32];
    float mf = fmaxf(mprev, mo);
    float fs = __expf(mprev - mf);
    float fo = __expf(mo - mf);
    float rinv = fs / (fs * lsum + fo * lo2);

    float* mrg = (float*)(smem + 2048);  // 4KB offset in 64KB region; no overlap with scr
    if (kh == 1) {
#pragma unroll
        for (int ct = 0; ct < 4; ++ct)
#pragma unroll
            for (int r = 0; r < 16; ++r) {
                int ch = ct * 32 + (r & 3) + 8 * (r >> 2) + 4 * h;
                mrg[qh * 4096 + ch * 32 + m32] = accO[ct][r] * rinv;
            }
    }
    __syncthreads();
    if (kh == 0) {
        float* O = out + (size_t)b * CH * NPIX;
#pragma unroll
        for (int ct = 0; ct < 4; ++ct)
#pragma unroll
            for (int r = 0; r < 16; ++r) {
                int ch = ct * 32 + (r & 3) + 8 * (r >> 2) + 4 * h;
                O[(size_t)ch * NPIX + i0g + qh * 32 + m32] =
                    accO[ct][r] * rinv + mrg[qh * 4096 + ch * 32 + m32];
            }
    }
}

extern "C" void kernel_launch(void* const* d_in, const int* in_sizes, int n_in,
                              void* d_out, int out_size, void* d_ws, size_t ws_size,
                              hipStream_t stream) {
    const float* x1 = (const float*)d_in[0];
    const float* x2 = (const float*)d_in[1];
    const float* Wq = (const float*)d_in[2];
    const float* bq = (const float*)d_in[3];
    const float* Wk = (const float*)d_in[4];
    const float* bk = (const float*)d_in[5];
    const float* Wv = (const float*)d_in[6];
    const float* bv = (const float*)d_in[7];
    float* outp = (float*)d_out;

    const size_t N = (size_t)BATCH * NPIX * CH;
    hf* Qhi = (hf*)d_ws;
    hf* Qlo = Qhi + N;
    hf* Kf = Qhi + 2 * N;
    hf* Vf = Qhi + 3 * N;
    float* wt = (float*)(Qhi + 4 * N);

    wtrans_kernel<<<3, 256, 0, stream>>>(Wq, Wk, Wv, wt);
    qkv_kernel<<<3 * BATCH * (NPIX / 128), 256, 0, stream>>>(x1, x2, wt, bq, bk, bv,
                                                             Qhi, Qlo, Kf, Vf);
    attn_kernel<<<BATCH * (NPIX / 64), 256, 0, stream>>>(Qhi, Qlo, Kf, Vf, outp);
}